// Round 1
// baseline (727.504 us; speedup 1.0000x reference)
//
#include <hip/hip_runtime.h>
#include <float.h>
#include <math.h>

// Problem constants
#define B_SZ 1024
#define D_SZ 8192
#define C_SZ 345
#define F_SZ 512
#define PROTO_W 0.99f

// d_out layout (float32, flat, reference return order):
//   logits   [2048][345]  @ 0        (logits_q rows 0..1023, logits_q1 rows 1024..2047)
//   new_proto[345][512]   @ 706560
//   scores   [345][345]   @ 883200
//   labels   [1024]       @ 1002225  (stored as float)
//   feats    [2048][512]  @ 1003249  (feats_q rows 0..1023, feats_q1 rows 1024..2047)

// ---------------------------------------------------------------------------
// Kernel A: feats[2048][512] = X[2048][8192] @ W_enc[8192][512]   (fp32)
// 64x64 tile, BK=16, 256 threads, 4x4 register micro-tile per thread.
// grid = (512/64, 2048/64) = (8, 32) = 256 blocks (~1 per CU).
// ---------------------------------------------------------------------------
__global__ __launch_bounds__(256) void gemm_enc(
    const float* __restrict__ img_q, const float* __restrict__ img_q1,
    const float* __restrict__ W_enc, float* __restrict__ feats)
{
    __shared__ __align__(16) float As[16][68];  // [k][row], +pad
    __shared__ __align__(16) float Bs[16][68];  // [k][col], +pad (68%4==0 keeps f4 align)

    const int t = threadIdx.x;
    const int nBase = blockIdx.x * 64;
    const int mBase = blockIdx.y * 64;
    // whole 64-row tile comes from a single source (1024 % 64 == 0)
    const float* X = (mBase < B_SZ) ? (img_q + (size_t)mBase * D_SZ)
                                    : (img_q1 + (size_t)(mBase - B_SZ) * D_SZ);

    const int arow = t >> 2;            // 0..63
    const int ac4  = (t & 3) * 4;       // 0,4,8,12  (k offset)
    const int brow = t >> 4;            // 0..15     (k offset)
    const int bc4  = (t & 15) * 4;      // 0..60     (col offset)

    const int ty = (t >> 4) * 4;        // output row offset in tile: 0..60
    const int tx = (t & 15) * 4;        // output col offset in tile: 0..60

    float acc[4][4] = {};

    for (int k0 = 0; k0 < D_SZ; k0 += 16) {
        float4 av = *(const float4*)&X[(size_t)arow * D_SZ + k0 + ac4];
        float4 bv = *(const float4*)&W_enc[(size_t)(k0 + brow) * F_SZ + nBase + bc4];
        __syncthreads();  // previous iteration's LDS reads complete
        As[ac4 + 0][arow] = av.x;
        As[ac4 + 1][arow] = av.y;
        As[ac4 + 2][arow] = av.z;
        As[ac4 + 3][arow] = av.w;
        *(float4*)&Bs[brow][bc4] = bv;
        __syncthreads();
#pragma unroll
        for (int k = 0; k < 16; ++k) {
            float4 a = *(const float4*)&As[k][ty];
            float4 b = *(const float4*)&Bs[k][tx];
            acc[0][0] += a.x * b.x; acc[0][1] += a.x * b.y; acc[0][2] += a.x * b.z; acc[0][3] += a.x * b.w;
            acc[1][0] += a.y * b.x; acc[1][1] += a.y * b.y; acc[1][2] += a.y * b.z; acc[1][3] += a.y * b.w;
            acc[2][0] += a.z * b.x; acc[2][1] += a.z * b.y; acc[2][2] += a.z * b.z; acc[2][3] += a.z * b.w;
            acc[3][0] += a.w * b.x; acc[3][1] += a.w * b.y; acc[3][2] += a.w * b.z; acc[3][3] += a.w * b.w;
        }
    }

#pragma unroll
    for (int r = 0; r < 4; ++r) {
        float4 v = make_float4(acc[r][0], acc[r][1], acc[r][2], acc[r][3]);
        *(float4*)&feats[(size_t)(mBase + ty + r) * F_SZ + nBase + tx] = v;
    }
}

// ---------------------------------------------------------------------------
// Kernel B: logits[2048][345] = feats[2048][512] @ W_fc[512][345] + b_fc
// 8 rows per block, 256 threads; thread t computes cols t and t+256.
// ---------------------------------------------------------------------------
__global__ __launch_bounds__(256) void fc_logits(
    const float* __restrict__ feats, const float* __restrict__ W_fc,
    const float* __restrict__ b_fc, float* __restrict__ logits)
{
    __shared__ __align__(16) float fs[8][F_SZ];
    const int t = threadIdx.x;
    const int r0 = blockIdx.x * 8;
#pragma unroll
    for (int j = 0; j < 4; ++j) {
        int f4 = t + j * 256;            // 0..1023 float4s
        int row = f4 >> 7;
        int col = (f4 & 127) * 4;
        *(float4*)&fs[row][col] = *(const float4*)&feats[(size_t)(r0 + row) * F_SZ + col];
    }
    __syncthreads();

    const int c0 = t;
    const int c1 = t + 256;
    float acc0[8] = {};
    float acc1[8] = {};
    for (int k = 0; k < F_SZ; ++k) {
        float w0 = W_fc[k * C_SZ + c0];
        float w1 = (c1 < C_SZ) ? W_fc[k * C_SZ + c1] : 0.0f;
#pragma unroll
        for (int r = 0; r < 8; ++r) {
            float f = fs[r][k];
            acc0[r] += f * w0;
            acc1[r] += f * w1;
        }
    }
    float bb0 = b_fc[c0];
#pragma unroll
    for (int r = 0; r < 8; ++r)
        logits[(size_t)(r0 + r) * C_SZ + c0] = acc0[r] + bb0;
    if (c1 < C_SZ) {
        float bb1 = b_fc[c1];
#pragma unroll
        for (int r = 0; r < 8; ++r)
            logits[(size_t)(r0 + r) * C_SZ + c1] = acc1[r] + bb1;
    }
}

// ---------------------------------------------------------------------------
// Kernel C: labels[i] = argmax over {c: partial_Y[i,c]!=0} of logits_q[i,c]
// (softmax + positive normalization preserve argmax; first index on ties).
// One wave (64 threads) per row.
// ---------------------------------------------------------------------------
__global__ __launch_bounds__(64) void argmax_labels(
    const float* __restrict__ logits, const float* __restrict__ partial_Y,
    float* __restrict__ labels_f)
{
    const int i = blockIdx.x;
    const int lane = threadIdx.x;
    float best = -FLT_MAX;
    int bidx = C_SZ;
    for (int c = lane; c < C_SZ; c += 64) {
        if (partial_Y[(size_t)i * C_SZ + c] != 0.0f) {
            float v = logits[(size_t)i * C_SZ + c];
            if (v > best || (v == best && c < bidx)) { best = v; bidx = c; }
        }
    }
#pragma unroll
    for (int off = 32; off; off >>= 1) {
        float ov = __shfl_down(best, off);
        int oi = __shfl_down(bidx, off);
        if (ov > best || (ov == best && oi < bidx)) { best = ov; bidx = oi; }
    }
    if (lane == 0) labels_f[i] = (float)bidx;
}

// ---------------------------------------------------------------------------
// Kernel D: sequential-EMA closed form per class, then L2 renorm.
// Block c (345 blocks), 512 threads = one feature each.
// k-th member (row order) of class with m members: coef = 0.01*0.99^(m-1-k);
// new_proto = 0.99^m * proto + sum(coef*feats_q), normalized.
// ---------------------------------------------------------------------------
__global__ __launch_bounds__(512) void proto_update(
    const float* __restrict__ labels_f, const float* __restrict__ feats_q,
    const float* __restrict__ proto, float* __restrict__ new_proto)
{
    __shared__ int lab[B_SZ];
    __shared__ int cnt;
    __shared__ float red[8];
    __shared__ float rinv_s;

    const int c = blockIdx.x;
    const int t = threadIdx.x;
    if (t == 0) cnt = 0;
    for (int i = t; i < B_SZ; i += 512) lab[i] = (int)labels_f[i];
    __syncthreads();

    int local = 0;
    for (int i = t; i < B_SZ; i += 512) local += (lab[i] == c);
    if (local) atomicAdd(&cnt, local);
    __syncthreads();
    const int m = cnt;

    float acc = 0.0f;
    int k = 0;
    for (int i = 0; i < B_SZ; ++i) {
        if (lab[i] == c) {
            float coef = (1.0f - PROTO_W) * powf(PROTO_W, (float)(m - 1 - k));
            acc += coef * feats_q[(size_t)i * F_SZ + t];
            ++k;
        }
    }
    float val = powf(PROTO_W, (float)m) * proto[(size_t)c * F_SZ + t] + acc;

    // L2 norm over 512 lanes
    float sq = val * val;
#pragma unroll
    for (int off = 32; off; off >>= 1) sq += __shfl_down(sq, off);
    if ((t & 63) == 0) red[t >> 6] = sq;
    __syncthreads();
    if (t == 0) {
        float s = 0.0f;
#pragma unroll
        for (int w = 0; w < 8; ++w) s += red[w];
        rinv_s = 1.0f / sqrtf(s);
    }
    __syncthreads();
    new_proto[(size_t)c * F_SZ + t] = val * rinv_s;
}

// ---------------------------------------------------------------------------
// Kernel E: scores[345][345] = new_proto[345][512] @ W_fc + b_fc
// Same structure as fc_logits, with row bounds.
// ---------------------------------------------------------------------------
__global__ __launch_bounds__(256) void fc_proto(
    const float* __restrict__ new_proto, const float* __restrict__ W_fc,
    const float* __restrict__ b_fc, float* __restrict__ scores)
{
    __shared__ __align__(16) float ps[8][F_SZ];
    const int t = threadIdx.x;
    const int r0 = blockIdx.x * 8;
#pragma unroll
    for (int j = 0; j < 4; ++j) {
        int f4 = t + j * 256;
        int row = f4 >> 7;
        int col = (f4 & 127) * 4;
        int rr = r0 + row;
        if (rr >= C_SZ) rr = C_SZ - 1;  // clamp (avoid OOB; values unused)
        *(float4*)&ps[row][col] = *(const float4*)&new_proto[(size_t)rr * F_SZ + col];
    }
    __syncthreads();

    const int c0 = t;
    const int c1 = t + 256;
    float acc0[8] = {};
    float acc1[8] = {};
    for (int k = 0; k < F_SZ; ++k) {
        float w0 = W_fc[k * C_SZ + c0];
        float w1 = (c1 < C_SZ) ? W_fc[k * C_SZ + c1] : 0.0f;
#pragma unroll
        for (int r = 0; r < 8; ++r) {
            float f = ps[r][k];
            acc0[r] += f * w0;
            acc1[r] += f * w1;
        }
    }
    float bb0 = b_fc[c0];
    float bb1 = (c1 < C_SZ) ? b_fc[c1] : 0.0f;
#pragma unroll
    for (int r = 0; r < 8; ++r) {
        if (r0 + r < C_SZ) {
            scores[(size_t)(r0 + r) * C_SZ + c0] = acc0[r] + bb0;
            if (c1 < C_SZ) scores[(size_t)(r0 + r) * C_SZ + c1] = acc1[r] + bb1;
        }
    }
}

// ---------------------------------------------------------------------------
extern "C" void kernel_launch(void* const* d_in, const int* in_sizes, int n_in,
                              void* d_out, int out_size, void* d_ws, size_t ws_size,
                              hipStream_t stream)
{
    const float* img_q     = (const float*)d_in[0];
    const float* img_q1    = (const float*)d_in[1];
    const float* partial_Y = (const float*)d_in[2];
    const float* W_enc     = (const float*)d_in[3];
    const float* W_fc      = (const float*)d_in[4];
    const float* b_fc      = (const float*)d_in[5];
    const float* proto     = (const float*)d_in[6];

    float* out       = (float*)d_out;
    float* logits    = out;            // [2048][345]
    float* new_proto = out + 706560;   // [345][512]
    float* scores    = out + 883200;   // [345][345]
    float* labels_f  = out + 1002225;  // [1024]
    float* feats     = out + 1003249;  // [2048][512]

    hipLaunchKernelGGL(gemm_enc, dim3(8, 32), dim3(256), 0, stream,
                       img_q, img_q1, W_enc, feats);
    hipLaunchKernelGGL(fc_logits, dim3(256), dim3(256), 0, stream,
                       feats, W_fc, b_fc, logits);
    hipLaunchKernelGGL(argmax_labels, dim3(1024), dim3(64), 0, stream,
                       logits, partial_Y, labels_f);
    hipLaunchKernelGGL(proto_update, dim3(345), dim3(512), 0, stream,
                       labels_f, feats /* rows 0..1023 = feats_q */, proto, new_proto);
    hipLaunchKernelGGL(fc_proto, dim3(44), dim3(256), 0, stream,
                       new_proto, W_fc, b_fc, scores);
}

// Round 2
// 526.281 us; speedup vs baseline: 1.3824x; 1.3824x over previous
//
#include <hip/hip_runtime.h>
#include <float.h>
#include <math.h>

// Problem constants
#define B_SZ 1024
#define D_SZ 8192
#define C_SZ 345
#define F_SZ 512
#define PROTO_W 0.99f

// d_out layout (float32, flat, reference return order):
//   logits   [2048][345]  @ 0
//   new_proto[345][512]   @ 706560
//   scores   [345][345]   @ 883200
//   labels   [1024]       @ 1002225  (stored as float)
//   feats    [2048][512]  @ 1003249

typedef short bf16x8 __attribute__((ext_vector_type(8)));
typedef float f32x4  __attribute__((ext_vector_type(4)));

#define LDA 40   // padded LDS row stride in bf16 elems (80 B, multiple of 16 B)

__device__ __forceinline__ short f32_to_bf16_rne(float x) {
    unsigned u = __float_as_uint(x);
    unsigned r = (u + 0x7FFFu + ((u >> 16) & 1u)) >> 16;
    return (short)r;
}
__device__ __forceinline__ float bf16_to_f32(short h) {
    return __uint_as_float(((unsigned)(unsigned short)h) << 16);
}
// split x into hi (RNE bf16) and lo (truncated bf16 of residual)
__device__ __forceinline__ void split_bf16(float x, short& hi, short& lo) {
    unsigned u = __float_as_uint(x);
    unsigned r = (u + 0x7FFFu + ((u >> 16) & 1u)) >> 16;
    hi = (short)r;
    float hf = __uint_as_float(r << 16);
    lo = (short)(__float_as_uint(x - hf) >> 16);
}

// ---------------------------------------------------------------------------
// Kernel A: feats[2048][512] = X[2048][8192] @ W_enc[8192][512]
// bf16x3 split-precision MFMA: C = Ah*Bh + Ah*Bl + Al*Bh  (~fp32 accuracy).
// 64x64 tile, BK=32, 256 threads (4 waves, each a 32x32 quadrant),
// double-buffered LDS, on-the-fly fp32 -> bf16 hi/lo conversion,
// B transposed into [n][k] with XOR swizzle on the 16B k-group.
// grid = (8, 32) = 256 blocks (1/CU).
// ---------------------------------------------------------------------------
__global__ __launch_bounds__(256) void gemm_enc_mfma(
    const float* __restrict__ img_q, const float* __restrict__ img_q1,
    const float* __restrict__ W_enc, float* __restrict__ feats)
{
    __shared__ __align__(16) short Ah[2][64 * LDA];
    __shared__ __align__(16) short Al[2][64 * LDA];
    __shared__ __align__(16) short Bh[2][64 * LDA];
    __shared__ __align__(16) short Bl[2][64 * LDA];

    const int t = threadIdx.x;
    const int nBase = blockIdx.x * 64;
    const int mBase = blockIdx.y * 64;
    const float* X = (mBase < B_SZ) ? (img_q + (size_t)mBase * D_SZ)
                                    : (img_q1 + (size_t)(mBase - B_SZ) * D_SZ);

    // A staging: thread -> (row, 8-wide k-group)
    const int arow = t >> 2;           // 0..63
    const int akq  = t & 3;            // 0..3
    // B staging: thread -> (n, 8-wide k-group), writes transposed [n][k]
    const int bn   = t & 63;           // 0..63
    const int bkg  = t >> 6;           // 0..3 (uniform per wave)
    const int bsw  = (bkg + (bn >> 3)) & 3;   // swizzled k-group slot

    const float* aptr = X + (size_t)arow * D_SZ + akq * 8;
    const float* bptr = W_enc + (size_t)(bkg * 8) * F_SZ + nBase + bn;

    // MFMA wave/lane coords
    const int wave = t >> 6;
    const int lane = t & 63;
    const int mo   = (wave >> 1) * 32;
    const int no   = (wave & 1) * 32;
    const int lrow = lane & 15;
    const int lkg  = lane >> 4;        // 0..3

    f32x4 acc[2][2] = {};

    // ---- stage step 0 ----
    {
        float4 av0 = *(const float4*)(aptr);
        float4 av1 = *(const float4*)(aptr + 4);
        float bv[8];
#pragma unroll
        for (int i = 0; i < 8; ++i) bv[i] = bptr[(size_t)i * F_SZ];
        bf16x8 h, l;
        float va[8] = {av0.x, av0.y, av0.z, av0.w, av1.x, av1.y, av1.z, av1.w};
#pragma unroll
        for (int i = 0; i < 8; ++i) { short hh, ll; split_bf16(va[i], hh, ll); h[i] = hh; l[i] = ll; }
        *(bf16x8*)&Ah[0][arow * LDA + akq * 8] = h;
        *(bf16x8*)&Al[0][arow * LDA + akq * 8] = l;
#pragma unroll
        for (int i = 0; i < 8; ++i) { short hh, ll; split_bf16(bv[i], hh, ll); h[i] = hh; l[i] = ll; }
        *(bf16x8*)&Bh[0][bn * LDA + bsw * 8] = h;
        *(bf16x8*)&Bl[0][bn * LDA + bsw * 8] = l;
    }
    __syncthreads();

    // fragment LDS offsets (constant over the k-loop)
    const int aoff0 = (mo + 0 * 16 + lrow) * LDA + lkg * 8;
    const int aoff1 = (mo + 1 * 16 + lrow) * LDA + lkg * 8;
    const int bnn0  = no + 0 * 16 + lrow;
    const int bnn1  = no + 1 * 16 + lrow;
    const int boff0 = bnn0 * LDA + ((lkg + (bnn0 >> 3)) & 3) * 8;
    const int boff1 = bnn1 * LDA + ((lkg + (bnn1 >> 3)) & 3) * 8;

    int buf = 0;
    for (int s = 0; s < 256; ++s) {
        // issue next step's global loads early (in flight during MFMA)
        float4 na0, na1; float nb[8];
        const bool more = (s + 1 < 256);
        if (more) {
            const float* ap = aptr + (size_t)(s + 1) * 32;
            na0 = *(const float4*)(ap);
            na1 = *(const float4*)(ap + 4);
            const float* bp = bptr + (size_t)(s + 1) * 32 * F_SZ;
#pragma unroll
            for (int i = 0; i < 8; ++i) nb[i] = bp[(size_t)i * F_SZ];
        }

        bf16x8 a0h = *(bf16x8*)&Ah[buf][aoff0];
        bf16x8 a1h = *(bf16x8*)&Ah[buf][aoff1];
        bf16x8 a0l = *(bf16x8*)&Al[buf][aoff0];
        bf16x8 a1l = *(bf16x8*)&Al[buf][aoff1];
        bf16x8 b0h = *(bf16x8*)&Bh[buf][boff0];
        bf16x8 b1h = *(bf16x8*)&Bh[buf][boff1];
        bf16x8 b0l = *(bf16x8*)&Bl[buf][boff0];
        bf16x8 b1l = *(bf16x8*)&Bl[buf][boff1];

        acc[0][0] = __builtin_amdgcn_mfma_f32_16x16x32_bf16(a0h, b0h, acc[0][0], 0, 0, 0);
        acc[0][1] = __builtin_amdgcn_mfma_f32_16x16x32_bf16(a0h, b1h, acc[0][1], 0, 0, 0);
        acc[1][0] = __builtin_amdgcn_mfma_f32_16x16x32_bf16(a1h, b0h, acc[1][0], 0, 0, 0);
        acc[1][1] = __builtin_amdgcn_mfma_f32_16x16x32_bf16(a1h, b1h, acc[1][1], 0, 0, 0);
        acc[0][0] = __builtin_amdgcn_mfma_f32_16x16x32_bf16(a0h, b0l, acc[0][0], 0, 0, 0);
        acc[0][1] = __builtin_amdgcn_mfma_f32_16x16x32_bf16(a0h, b1l, acc[0][1], 0, 0, 0);
        acc[1][0] = __builtin_amdgcn_mfma_f32_16x16x32_bf16(a1h, b0l, acc[1][0], 0, 0, 0);
        acc[1][1] = __builtin_amdgcn_mfma_f32_16x16x32_bf16(a1h, b1l, acc[1][1], 0, 0, 0);
        acc[0][0] = __builtin_amdgcn_mfma_f32_16x16x32_bf16(a0l, b0h, acc[0][0], 0, 0, 0);
        acc[0][1] = __builtin_amdgcn_mfma_f32_16x16x32_bf16(a0l, b1h, acc[0][1], 0, 0, 0);
        acc[1][0] = __builtin_amdgcn_mfma_f32_16x16x32_bf16(a1l, b0h, acc[1][0], 0, 0, 0);
        acc[1][1] = __builtin_amdgcn_mfma_f32_16x16x32_bf16(a1l, b1h, acc[1][1], 0, 0, 0);

        if (more) {
            bf16x8 h, l;
            float va[8] = {na0.x, na0.y, na0.z, na0.w, na1.x, na1.y, na1.z, na1.w};
#pragma unroll
            for (int i = 0; i < 8; ++i) { short hh, ll; split_bf16(va[i], hh, ll); h[i] = hh; l[i] = ll; }
            *(bf16x8*)&Ah[buf ^ 1][arow * LDA + akq * 8] = h;
            *(bf16x8*)&Al[buf ^ 1][arow * LDA + akq * 8] = l;
#pragma unroll
            for (int i = 0; i < 8; ++i) { short hh, ll; split_bf16(nb[i], hh, ll); h[i] = hh; l[i] = ll; }
            *(bf16x8*)&Bh[buf ^ 1][bn * LDA + bsw * 8] = h;
            *(bf16x8*)&Bl[buf ^ 1][bn * LDA + bsw * 8] = l;
        }
        __syncthreads();
        buf ^= 1;
    }

    // epilogue: C/D layout col = lane&15, row = (lane>>4)*4 + reg
#pragma unroll
    for (int f = 0; f < 2; ++f) {
#pragma unroll
        for (int g = 0; g < 2; ++g) {
            const int col  = nBase + no + g * 16 + (lane & 15);
            const int row0 = mBase + mo + f * 16 + (lane >> 4) * 4;
#pragma unroll
            for (int r = 0; r < 4; ++r)
                feats[(size_t)(row0 + r) * F_SZ + col] = acc[f][g][r];
        }
    }
}

// ---------------------------------------------------------------------------
// Kernel B: logits[2048][345] = feats[2048][512] @ W_fc[512][345] + b_fc
// ---------------------------------------------------------------------------
__global__ __launch_bounds__(256) void fc_logits(
    const float* __restrict__ feats, const float* __restrict__ W_fc,
    const float* __restrict__ b_fc, float* __restrict__ logits)
{
    __shared__ __align__(16) float fs[8][F_SZ];
    const int t = threadIdx.x;
    const int r0 = blockIdx.x * 8;
#pragma unroll
    for (int j = 0; j < 4; ++j) {
        int f4 = t + j * 256;
        int row = f4 >> 7;
        int col = (f4 & 127) * 4;
        *(float4*)&fs[row][col] = *(const float4*)&feats[(size_t)(r0 + row) * F_SZ + col];
    }
    __syncthreads();

    const int c0 = t;
    const int c1 = t + 256;
    float acc0[8] = {};
    float acc1[8] = {};
    for (int k = 0; k < F_SZ; ++k) {
        float w0 = W_fc[k * C_SZ + c0];
        float w1 = (c1 < C_SZ) ? W_fc[k * C_SZ + c1] : 0.0f;
#pragma unroll
        for (int r = 0; r < 8; ++r) {
            float f = fs[r][k];
            acc0[r] += f * w0;
            acc1[r] += f * w1;
        }
    }
    float bb0 = b_fc[c0];
#pragma unroll
    for (int r = 0; r < 8; ++r)
        logits[(size_t)(r0 + r) * C_SZ + c0] = acc0[r] + bb0;
    if (c1 < C_SZ) {
        float bb1 = b_fc[c1];
#pragma unroll
        for (int r = 0; r < 8; ++r)
            logits[(size_t)(r0 + r) * C_SZ + c1] = acc1[r] + bb1;
    }
}

// ---------------------------------------------------------------------------
// Kernel C: masked argmax (softmax+renorm preserve argmax; first index wins)
// ---------------------------------------------------------------------------
__global__ __launch_bounds__(64) void argmax_labels(
    const float* __restrict__ logits, const float* __restrict__ partial_Y,
    float* __restrict__ labels_f)
{
    const int i = blockIdx.x;
    const int lane = threadIdx.x;
    float best = -FLT_MAX;
    int bidx = C_SZ;
    for (int c = lane; c < C_SZ; c += 64) {
        if (partial_Y[(size_t)i * C_SZ + c] != 0.0f) {
            float v = logits[(size_t)i * C_SZ + c];
            if (v > best || (v == best && c < bidx)) { best = v; bidx = c; }
        }
    }
#pragma unroll
    for (int off = 32; off; off >>= 1) {
        float ov = __shfl_down(best, off);
        int oi = __shfl_down(bidx, off);
        if (ov > best || (ov == best && oi < bidx)) { best = ov; bidx = oi; }
    }
    if (lane == 0) labels_f[i] = (float)bidx;
}

// ---------------------------------------------------------------------------
// Kernel D: literal sequential EMA per class (matches reference recursion),
// then L2 renorm. lab[i] is block-uniform -> scalar branch, no divergence.
// ---------------------------------------------------------------------------
__global__ __launch_bounds__(512) void proto_update(
    const float* __restrict__ labels_f, const float* __restrict__ feats_q,
    const float* __restrict__ proto, float* __restrict__ new_proto)
{
    __shared__ int lab[B_SZ];
    __shared__ float red[8];
    __shared__ float rinv_s;

    const int c = blockIdx.x;
    const int t = threadIdx.x;
    for (int i = t; i < B_SZ; i += 512) lab[i] = (int)labels_f[i];
    __syncthreads();

    float val = proto[(size_t)c * F_SZ + t];
    for (int i = 0; i < B_SZ; ++i) {
        if (lab[i] == c)
            val = PROTO_W * val + (1.0f - PROTO_W) * feats_q[(size_t)i * F_SZ + t];
    }

    float sq = val * val;
#pragma unroll
    for (int off = 32; off; off >>= 1) sq += __shfl_down(sq, off);
    if ((t & 63) == 0) red[t >> 6] = sq;
    __syncthreads();
    if (t == 0) {
        float s = 0.0f;
#pragma unroll
        for (int w = 0; w < 8; ++w) s += red[w];
        rinv_s = 1.0f / sqrtf(s);
    }
    __syncthreads();
    new_proto[(size_t)c * F_SZ + t] = val * rinv_s;
}

// ---------------------------------------------------------------------------
// Kernel E: scores[345][345] = new_proto @ W_fc + b_fc
// ---------------------------------------------------------------------------
__global__ __launch_bounds__(256) void fc_proto(
    const float* __restrict__ new_proto, const float* __restrict__ W_fc,
    const float* __restrict__ b_fc, float* __restrict__ scores)
{
    __shared__ __align__(16) float ps[8][F_SZ];
    const int t = threadIdx.x;
    const int r0 = blockIdx.x * 8;
#pragma unroll
    for (int j = 0; j < 4; ++j) {
        int f4 = t + j * 256;
        int row = f4 >> 7;
        int col = (f4 & 127) * 4;
        int rr = r0 + row;
        if (rr >= C_SZ) rr = C_SZ - 1;
        *(float4*)&ps[row][col] = *(const float4*)&new_proto[(size_t)rr * F_SZ + col];
    }
    __syncthreads();

    const int c0 = t;
    const int c1 = t + 256;
    float acc0[8] = {};
    float acc1[8] = {};
    for (int k = 0; k < F_SZ; ++k) {
        float w0 = W_fc[k * C_SZ + c0];
        float w1 = (c1 < C_SZ) ? W_fc[k * C_SZ + c1] : 0.0f;
#pragma unroll
        for (int r = 0; r < 8; ++r) {
            float f = ps[r][k];
            acc0[r] += f * w0;
            acc1[r] += f * w1;
        }
    }
    float bb0 = b_fc[c0];
    float bb1 = (c1 < C_SZ) ? b_fc[c1] : 0.0f;
#pragma unroll
    for (int r = 0; r < 8; ++r) {
        if (r0 + r < C_SZ) {
            scores[(size_t)(r0 + r) * C_SZ + c0] = acc0[r] + bb0;
            if (c1 < C_SZ) scores[(size_t)(r0 + r) * C_SZ + c1] = acc1[r] + bb1;
        }
    }
}

// ---------------------------------------------------------------------------
extern "C" void kernel_launch(void* const* d_in, const int* in_sizes, int n_in,
                              void* d_out, int out_size, void* d_ws, size_t ws_size,
                              hipStream_t stream)
{
    const float* img_q     = (const float*)d_in[0];
    const float* img_q1    = (const float*)d_in[1];
    const float* partial_Y = (const float*)d_in[2];
    const float* W_enc     = (const float*)d_in[3];
    const float* W_fc      = (const float*)d_in[4];
    const float* b_fc      = (const float*)d_in[5];
    const float* proto     = (const float*)d_in[6];

    float* out       = (float*)d_out;
    float* logits    = out;            // [2048][345]
    float* new_proto = out + 706560;   // [345][512]
    float* scores    = out + 883200;   // [345][345]
    float* labels_f  = out + 1002225;  // [1024]
    float* feats     = out + 1003249;  // [2048][512]

    hipLaunchKernelGGL(gemm_enc_mfma, dim3(8, 32), dim3(256), 0, stream,
                       img_q, img_q1, W_enc, feats);
    hipLaunchKernelGGL(fc_logits, dim3(256), dim3(256), 0, stream,
                       feats, W_fc, b_fc, logits);
    hipLaunchKernelGGL(argmax_labels, dim3(1024), dim3(64), 0, stream,
                       logits, partial_Y, labels_f);
    hipLaunchKernelGGL(proto_update, dim3(345), dim3(512), 0, stream,
                       labels_f, feats /* rows 0..1023 = feats_q */, proto, new_proto);
    hipLaunchKernelGGL(fc_proto, dim3(44), dim3(256), 0, stream,
                       new_proto, W_fc, b_fc, scores);
}

// Round 3
// 387.001 us; speedup vs baseline: 1.8799x; 1.3599x over previous
//
#include <hip/hip_runtime.h>
#include <float.h>
#include <math.h>

// Problem constants
#define B_SZ 1024
#define D_SZ 8192
#define C_SZ 345
#define F_SZ 512
#define PROTO_W 0.99f

// d_out layout (float32, flat, reference return order):
//   logits   [2048][345]  @ 0
//   new_proto[345][512]   @ 706560
//   scores   [345][345]   @ 883200
//   labels   [1024]       @ 1002225  (stored as float)
//   feats    [2048][512]  @ 1003249

// d_ws layout (bytes):
//   Xh  [2048][8192] bf16 @ 0          (33,554,432)
//   Xl  [2048][8192] bf16 @ 33554432
//   Wh  [512][8192]  bf16 @ 67108864   (tile-transposed: [n][k])
//   Wl  [512][8192]  bf16 @ 75497472
//   P   [2][2048][512] f32 @ 83886080  (split-K partials)
#define WS_XH 0
#define WS_XL 33554432u
#define WS_WH 67108864u
#define WS_WL 75497472u
#define WS_P  83886080u
#define WS_NEED 92274688u

typedef short bf16x8 __attribute__((ext_vector_type(8)));
typedef short short4v __attribute__((ext_vector_type(4)));
typedef short short8v __attribute__((ext_vector_type(8)));
typedef float f32x4  __attribute__((ext_vector_type(4)));

__device__ __forceinline__ void split_bf16(float x, short& hi, short& lo) {
    unsigned u = __float_as_uint(x);
    unsigned r = (u + 0x7FFFu + ((u >> 16) & 1u)) >> 16;
    hi = (short)r;
    float hf = __uint_as_float(r << 16);
    lo = (short)(__float_as_uint(x - hf) >> 16);
}

__device__ __forceinline__ void gl_lds16(const short* g, short* l) {
    __builtin_amdgcn_global_load_lds(
        (const __attribute__((address_space(1))) void*)g,
        (__attribute__((address_space(3))) void*)l, 16, 0, 0);
}

// ---------------------------------------------------------------------------
// convert_x: X fp32 -> Xh/Xl bf16 (hi = RNE, lo = trunc of residual)
// ---------------------------------------------------------------------------
__global__ __launch_bounds__(256) void convert_x(
    const float* __restrict__ img_q, const float* __restrict__ img_q1,
    short* __restrict__ Xh, short* __restrict__ Xl)
{
    const int HALF = (B_SZ * D_SZ) / 4;       // 2,097,152 float4 per input
    const int total = 2 * HALF;
    for (int i4 = blockIdx.x * 256 + threadIdx.x; i4 < total; i4 += gridDim.x * 256) {
        float4 v = (i4 < HALF) ? ((const float4*)img_q)[i4]
                               : ((const float4*)img_q1)[i4 - HALF];
        short4v h, l;
        short hh, ll;
        split_bf16(v.x, hh, ll); h.x = hh; l.x = ll;
        split_bf16(v.y, hh, ll); h.y = hh; l.y = ll;
        split_bf16(v.z, hh, ll); h.z = hh; l.z = ll;
        split_bf16(v.w, hh, ll); h.w = hh; l.w = ll;
        ((short4v*)Xh)[i4] = h;
        ((short4v*)Xl)[i4] = l;
    }
}

// ---------------------------------------------------------------------------
// convert_w: W_enc[k][n] fp32 -> Wh/Wl[n][k] bf16 (transposed via LDS tile)
// grid (8192/64, 512/64) = (128, 8), 256 threads
// ---------------------------------------------------------------------------
__global__ __launch_bounds__(256) void convert_w(
    const float* __restrict__ W_enc, short* __restrict__ Wh, short* __restrict__ Wl)
{
    __shared__ float tile[64][65];
    const int k0 = blockIdx.x * 64;
    const int n0 = blockIdx.y * 64;
    const int t = threadIdx.x;
    {
        const int kr = t >> 2;
        const int cb = (t & 3) * 16;
#pragma unroll
        for (int j = 0; j < 4; ++j) {
            float4 v = *(const float4*)&W_enc[(size_t)(k0 + kr) * F_SZ + n0 + cb + j * 4];
            tile[kr][cb + j * 4 + 0] = v.x;
            tile[kr][cb + j * 4 + 1] = v.y;
            tile[kr][cb + j * 4 + 2] = v.z;
            tile[kr][cb + j * 4 + 3] = v.w;
        }
    }
    __syncthreads();
    const int n = t >> 2;
#pragma unroll
    for (int cc = 0; cc < 2; ++cc) {
        const int ch = (t & 3) * 2 + cc;
        short8v h, l;
#pragma unroll
        for (int e = 0; e < 8; ++e) {
            short hh, ll;
            split_bf16(tile[ch * 8 + e][n], hh, ll);
            h[e] = hh; l[e] = ll;
        }
        size_t off = (size_t)(n0 + n) * D_SZ + k0 + ch * 8;
        *(short8v*)&Wh[off] = h;
        *(short8v*)&Wl[off] = l;
    }
}

// ---------------------------------------------------------------------------
// gemm_ws: P[ks] += A(64xK/2) @ B(K/2x64), bf16x3 split-precision from ws.
// 64x64 tile, BK=64, 256 threads (4 waves, 32x32 quadrant each), split-K=2.
// Staging: global_load_lds dwordx4, wave w stages array w (Ah/Al/Bh/Bl).
// LDS rows = 64 bf16 = 128 B; k-chunk XOR-swizzled by row&7 -> conflict-free
// ds_read_b128 (16 lanes cover all 32 banks, 2-way = free).
// grid (8, 32, 2) = 512 blocks = 2/CU.
// ---------------------------------------------------------------------------
__global__ __launch_bounds__(256) void gemm_ws(
    const short* __restrict__ Xh, const short* __restrict__ Xl,
    const short* __restrict__ Wh, const short* __restrict__ Wl,
    float* __restrict__ P)
{
    __shared__ __align__(16) short sAh[4096];
    __shared__ __align__(16) short sAl[4096];
    __shared__ __align__(16) short sBh[4096];
    __shared__ __align__(16) short sBl[4096];

    const int t = threadIdx.x;
    const int lane = t & 63;
    const int wave = t >> 6;
    const int nt = blockIdx.x;          // 0..7
    const int mt = blockIdx.y;          // 0..31
    const int ks = blockIdx.z;          // 0..1
    const int m0 = mt * 64;
    const int kbase = ks * 4096;

    // staging role: wave 0->Ah, 1->Al, 2->Bh, 3->Bl
    const short* gbase =
        (wave == 0) ? Xh + (size_t)m0 * D_SZ :
        (wave == 1) ? Xl + (size_t)m0 * D_SZ :
        (wave == 2) ? Wh + (size_t)nt * 64 * D_SZ :
                      Wl + (size_t)nt * 64 * D_SZ;
    short* lbase = (wave == 0) ? sAh : (wave == 1) ? sAl : (wave == 2) ? sBh : sBl;
    const int lrow8 = lane >> 3;                       // 0..7
    const int colOff = ((lane & 7) ^ lrow8) * 8;       // XOR swizzle (row&7 == lrow8)
    const short* gsrc = gbase + (size_t)lrow8 * D_SZ + kbase + colOff;

    // MFMA fragment coords
    const int mo = (wave >> 1) * 32;
    const int no = (wave & 1) * 32;
    const int lr = lane & 15;
    const int lkg = lane >> 4;          // 0..3
    const int x7 = lr & 7;
    const int sl0 = (0 + lkg) ^ x7;     // k-sub 0 chunk slot
    const int sl1 = (4 + lkg) ^ x7;     // k-sub 1 chunk slot
    const int ra0 = (mo + lr) * 64,      ra1 = (mo + 16 + lr) * 64;
    const int rb0 = (no + lr) * 64,      rb1 = (no + 16 + lr) * 64;
    const int a00 = ra0 + sl0 * 8, a01 = ra0 + sl1 * 8;
    const int a10 = ra1 + sl0 * 8, a11 = ra1 + sl1 * 8;
    const int b00 = rb0 + sl0 * 8, b01 = rb0 + sl1 * 8;
    const int b10 = rb1 + sl0 * 8, b11 = rb1 + sl1 * 8;

    f32x4 acc[2][2] = {};

#define MFMA_BF16 __builtin_amdgcn_mfma_f32_16x16x32_bf16
    for (int s = 0; s < 64; ++s) {
        __syncthreads();                 // prev-step LDS reads done
#pragma unroll
        for (int j = 0; j < 8; ++j)
            gl_lds16(gsrc + (size_t)(8 * j) * D_SZ + s * 64, lbase + j * 512);
        __syncthreads();                 // drains vmcnt before use
        {   // k-sub 0
            bf16x8 a0h = *(const bf16x8*)&sAh[a00];
            bf16x8 a1h = *(const bf16x8*)&sAh[a10];
            bf16x8 b0h = *(const bf16x8*)&sBh[b00];
            bf16x8 b1h = *(const bf16x8*)&sBh[b10];
            bf16x8 a0l = *(const bf16x8*)&sAl[a00];
            bf16x8 a1l = *(const bf16x8*)&sAl[a10];
            bf16x8 b0l = *(const bf16x8*)&sBl[b00];
            bf16x8 b1l = *(const bf16x8*)&sBl[b10];
            acc[0][0] = MFMA_BF16(a0h, b0h, acc[0][0], 0, 0, 0);
            acc[0][1] = MFMA_BF16(a0h, b1h, acc[0][1], 0, 0, 0);
            acc[1][0] = MFMA_BF16(a1h, b0h, acc[1][0], 0, 0, 0);
            acc[1][1] = MFMA_BF16(a1h, b1h, acc[1][1], 0, 0, 0);
            acc[0][0] = MFMA_BF16(a0h, b0l, acc[0][0], 0, 0, 0);
            acc[0][1] = MFMA_BF16(a0h, b1l, acc[0][1], 0, 0, 0);
            acc[1][0] = MFMA_BF16(a1h, b0l, acc[1][0], 0, 0, 0);
            acc[1][1] = MFMA_BF16(a1h, b1l, acc[1][1], 0, 0, 0);
            acc[0][0] = MFMA_BF16(a0l, b0h, acc[0][0], 0, 0, 0);
            acc[0][1] = MFMA_BF16(a0l, b1h, acc[0][1], 0, 0, 0);
            acc[1][0] = MFMA_BF16(a1l, b0h, acc[1][0], 0, 0, 0);
            acc[1][1] = MFMA_BF16(a1l, b1h, acc[1][1], 0, 0, 0);
        }
        {   // k-sub 1
            bf16x8 a0h = *(const bf16x8*)&sAh[a01];
            bf16x8 a1h = *(const bf16x8*)&sAh[a11];
            bf16x8 b0h = *(const bf16x8*)&sBh[b01];
            bf16x8 b1h = *(const bf16x8*)&sBh[b11];
            bf16x8 a0l = *(const bf16x8*)&sAl[a01];
            bf16x8 a1l = *(const bf16x8*)&sAl[a11];
            bf16x8 b0l = *(const bf16x8*)&sBl[b01];
            bf16x8 b1l = *(const bf16x8*)&sBl[b11];
            acc[0][0] = MFMA_BF16(a0h, b0h, acc[0][0], 0, 0, 0);
            acc[0][1] = MFMA_BF16(a0h, b1h, acc[0][1], 0, 0, 0);
            acc[1][0] = MFMA_BF16(a1h, b0h, acc[1][0], 0, 0, 0);
            acc[1][1] = MFMA_BF16(a1h, b1h, acc[1][1], 0, 0, 0);
            acc[0][0] = MFMA_BF16(a0h, b0l, acc[0][0], 0, 0, 0);
            acc[0][1] = MFMA_BF16(a0h, b1l, acc[0][1], 0, 0, 0);
            acc[1][0] = MFMA_BF16(a1h, b0l, acc[1][0], 0, 0, 0);
            acc[1][1] = MFMA_BF16(a1h, b1l, acc[1][1], 0, 0, 0);
            acc[0][0] = MFMA_BF16(a0l, b0h, acc[0][0], 0, 0, 0);
            acc[0][1] = MFMA_BF16(a0l, b1h, acc[0][1], 0, 0, 0);
            acc[1][0] = MFMA_BF16(a1l, b0h, acc[1][0], 0, 0, 0);
            acc[1][1] = MFMA_BF16(a1l, b1h, acc[1][1], 0, 0, 0);
        }
    }

    float* Pout = P + (size_t)ks * (2048u * 512u);
#pragma unroll
    for (int f = 0; f < 2; ++f)
#pragma unroll
        for (int g = 0; g < 2; ++g) {
            const int col  = nt * 64 + no + g * 16 + (lane & 15);
            const int row0 = m0 + mo + f * 16 + (lane >> 4) * 4;
#pragma unroll
            for (int r = 0; r < 4; ++r)
                Pout[(size_t)(row0 + r) * F_SZ + col] = acc[f][g][r];
        }
}

// ---------------------------------------------------------------------------
// reduce_feats: feats = P0 + P1 (scalar; feats base is only 4B-aligned)
// ---------------------------------------------------------------------------
__global__ __launch_bounds__(256) void reduce_feats(
    const float* __restrict__ P, float* __restrict__ feats)
{
    const int n = 2048 * 512;
    const float* P1 = P + n;
    for (int i = blockIdx.x * 256 + threadIdx.x; i < n; i += gridDim.x * 256)
        feats[i] = P[i] + P1[i];
}

// ---------------------------------------------------------------------------
// Fallback GEMM (R2, in-kernel conversion) for when ws_size is insufficient.
// ---------------------------------------------------------------------------
#define LDA 40
__global__ __launch_bounds__(256) void gemm_enc_mfma(
    const float* __restrict__ img_q, const float* __restrict__ img_q1,
    const float* __restrict__ W_enc, float* __restrict__ feats)
{
    __shared__ __align__(16) short Ah[2][64 * LDA];
    __shared__ __align__(16) short Al[2][64 * LDA];
    __shared__ __align__(16) short Bh[2][64 * LDA];
    __shared__ __align__(16) short Bl[2][64 * LDA];

    const int t = threadIdx.x;
    const int nBase = blockIdx.x * 64;
    const int mBase = blockIdx.y * 64;
    const float* X = (mBase < B_SZ) ? (img_q + (size_t)mBase * D_SZ)
                                    : (img_q1 + (size_t)(mBase - B_SZ) * D_SZ);
    const int arow = t >> 2;
    const int akq  = t & 3;
    const int bn   = t & 63;
    const int bkg  = t >> 6;
    const int bsw  = (bkg + (bn >> 3)) & 3;
    const float* aptr = X + (size_t)arow * D_SZ + akq * 8;
    const float* bptr = W_enc + (size_t)(bkg * 8) * F_SZ + nBase + bn;
    const int wave = t >> 6;
    const int lane = t & 63;
    const int mo   = (wave >> 1) * 32;
    const int no   = (wave & 1) * 32;
    const int lrow = lane & 15;
    const int lkg  = lane >> 4;
    f32x4 acc[2][2] = {};
    {
        float4 av0 = *(const float4*)(aptr);
        float4 av1 = *(const float4*)(aptr + 4);
        float bv[8];
#pragma unroll
        for (int i = 0; i < 8; ++i) bv[i] = bptr[(size_t)i * F_SZ];
        bf16x8 h, l;
        float va[8] = {av0.x, av0.y, av0.z, av0.w, av1.x, av1.y, av1.z, av1.w};
#pragma unroll
        for (int i = 0; i < 8; ++i) { short hh, ll; split_bf16(va[i], hh, ll); h[i] = hh; l[i] = ll; }
        *(bf16x8*)&Ah[0][arow * LDA + akq * 8] = h;
        *(bf16x8*)&Al[0][arow * LDA + akq * 8] = l;
#pragma unroll
        for (int i = 0; i < 8; ++i) { short hh, ll; split_bf16(bv[i], hh, ll); h[i] = hh; l[i] = ll; }
        *(bf16x8*)&Bh[0][bn * LDA + bsw * 8] = h;
        *(bf16x8*)&Bl[0][bn * LDA + bsw * 8] = l;
    }
    __syncthreads();
    const int aoff0 = (mo + lrow) * LDA + lkg * 8;
    const int aoff1 = (mo + 16 + lrow) * LDA + lkg * 8;
    const int bnn0  = no + lrow;
    const int bnn1  = no + 16 + lrow;
    const int boff0 = bnn0 * LDA + ((lkg + (bnn0 >> 3)) & 3) * 8;
    const int boff1 = bnn1 * LDA + ((lkg + (bnn1 >> 3)) & 3) * 8;
    int buf = 0;
    for (int s = 0; s < 256; ++s) {
        float4 na0, na1; float nb[8];
        const bool more = (s + 1 < 256);
        if (more) {
            const float* ap = aptr + (size_t)(s + 1) * 32;
            na0 = *(const float4*)(ap);
            na1 = *(const float4*)(ap + 4);
            const float* bp = bptr + (size_t)(s + 1) * 32 * F_SZ;
#pragma unroll
            for (int i = 0; i < 8; ++i) nb[i] = bp[(size_t)i * F_SZ];
        }
        bf16x8 a0h = *(bf16x8*)&Ah[buf][aoff0];
        bf16x8 a1h = *(bf16x8*)&Ah[buf][aoff1];
        bf16x8 a0l = *(bf16x8*)&Al[buf][aoff0];
        bf16x8 a1l = *(bf16x8*)&Al[buf][aoff1];
        bf16x8 b0h = *(bf16x8*)&Bh[buf][boff0];
        bf16x8 b1h = *(bf16x8*)&Bh[buf][boff1];
        bf16x8 b0l = *(bf16x8*)&Bl[buf][boff0];
        bf16x8 b1l = *(bf16x8*)&Bl[buf][boff1];
        acc[0][0] = MFMA_BF16(a0h, b0h, acc[0][0], 0, 0, 0);
        acc[0][1] = MFMA_BF16(a0h, b1h, acc[0][1], 0, 0, 0);
        acc[1][0] = MFMA_BF16(a1h, b0h, acc[1][0], 0, 0, 0);
        acc[1][1] = MFMA_BF16(a1h, b1h, acc[1][1], 0, 0, 0);
        acc[0][0] = MFMA_BF16(a0h, b0l, acc[0][0], 0, 0, 0);
        acc[0][1] = MFMA_BF16(a0h, b1l, acc[0][1], 0, 0, 0);
        acc[1][0] = MFMA_BF16(a1h, b0l, acc[1][0], 0, 0, 0);
        acc[1][1] = MFMA_BF16(a1h, b1l, acc[1][1], 0, 0, 0);
        acc[0][0] = MFMA_BF16(a0l, b0h, acc[0][0], 0, 0, 0);
        acc[0][1] = MFMA_BF16(a0l, b1h, acc[0][1], 0, 0, 0);
        acc[1][0] = MFMA_BF16(a1l, b0h, acc[1][0], 0, 0, 0);
        acc[1][1] = MFMA_BF16(a1l, b1h, acc[1][1], 0, 0, 0);
        if (more) {
            bf16x8 h, l;
            float va[8] = {na0.x, na0.y, na0.z, na0.w, na1.x, na1.y, na1.z, na1.w};
#pragma unroll
            for (int i = 0; i < 8; ++i) { short hh, ll; split_bf16(va[i], hh, ll); h[i] = hh; l[i] = ll; }
            *(bf16x8*)&Ah[buf ^ 1][arow * LDA + akq * 8] = h;
            *(bf16x8*)&Al[buf ^ 1][arow * LDA + akq * 8] = l;
#pragma unroll
            for (int i = 0; i < 8; ++i) { short hh, ll; split_bf16(nb[i], hh, ll); h[i] = hh; l[i] = ll; }
            *(bf16x8*)&Bh[buf ^ 1][bn * LDA + bsw * 8] = h;
            *(bf16x8*)&Bl[buf ^ 1][bn * LDA + bsw * 8] = l;
        }
        __syncthreads();
        buf ^= 1;
    }
#pragma unroll
    for (int f = 0; f < 2; ++f)
#pragma unroll
        for (int g = 0; g < 2; ++g) {
            const int col  = nBase + no + g * 16 + (lane & 15);
            const int row0 = mBase + mo + f * 16 + (lane >> 4) * 4;
#pragma unroll
            for (int r = 0; r < 4; ++r)
                feats[(size_t)(row0 + r) * F_SZ + col] = acc[f][g][r];
        }
}

// ---------------------------------------------------------------------------
// fc_logits_fused: logits = feats @ W_fc + b_fc; for rows < 1024 also the
// masked argmax -> labels. 4 rows/block, grid 512, 256 threads.
// ---------------------------------------------------------------------------
__global__ __launch_bounds__(256) void fc_logits_fused(
    const float* __restrict__ feats, const float* __restrict__ W_fc,
    const float* __restrict__ b_fc, const float* __restrict__ partial_Y,
    float* __restrict__ logits, float* __restrict__ labels_f)
{
    __shared__ __align__(16) float fs[4][F_SZ];
    __shared__ float redv[4];
    __shared__ int   redi[4];
    const int t = threadIdx.x;
    const int r0 = blockIdx.x * 4;
#pragma unroll
    for (int j = 0; j < 2; ++j) {
        int f4 = t + j * 256;           // 0..511 (4 rows x 128 float4)
        int row = f4 >> 7;
        int col = (f4 & 127) * 4;
        *(float4*)&fs[row][col] = *(const float4*)&feats[(size_t)(r0 + row) * F_SZ + col];
    }
    __syncthreads();
    const int c0 = t;
    const int c1 = t + 256;
    float acc0[4] = {};
    float acc1[4] = {};
#pragma unroll 4
    for (int k = 0; k < F_SZ; ++k) {
        float w0 = W_fc[k * C_SZ + c0];
        float w1 = (c1 < C_SZ) ? W_fc[k * C_SZ + c1] : 0.0f;
#pragma unroll
        for (int r = 0; r < 4; ++r) {
            float f = fs[r][k];
            acc0[r] += f * w0;
            acc1[r] += f * w1;
        }
    }
    float v0[4], v1[4];
    const float bb0 = b_fc[c0];
    const float bb1 = (c1 < C_SZ) ? b_fc[c1] : 0.0f;
#pragma unroll
    for (int r = 0; r < 4; ++r) {
        v0[r] = acc0[r] + bb0;
        logits[(size_t)(r0 + r) * C_SZ + c0] = v0[r];
        if (c1 < C_SZ) {
            v1[r] = acc1[r] + bb1;
            logits[(size_t)(r0 + r) * C_SZ + c1] = v1[r];
        }
    }
    if (r0 < B_SZ) {   // argmax for pseudo-labels (rows 0..1023)
#pragma unroll
        for (int r = 0; r < 4; ++r) {
            const int row = r0 + r;
            float best = -FLT_MAX; int bi = C_SZ;
            if (partial_Y[(size_t)row * C_SZ + c0] != 0.0f) { best = v0[r]; bi = c0; }
            if (c1 < C_SZ && partial_Y[(size_t)row * C_SZ + c1] != 0.0f && v1[r] > best) {
                best = v1[r]; bi = c1;
            }
#pragma unroll
            for (int off = 32; off; off >>= 1) {
                float ov = __shfl_down(best, off);
                int oi = __shfl_down(bi, off);
                if (ov > best || (ov == best && oi < bi)) { best = ov; bi = oi; }
            }
            if ((t & 63) == 0) { redv[t >> 6] = best; redi[t >> 6] = bi; }
            __syncthreads();
            if (t == 0) {
                float bb = redv[0]; int ii = redi[0];
#pragma unroll
                for (int w = 1; w < 4; ++w)
                    if (redv[w] > bb || (redv[w] == bb && redi[w] < ii)) { bb = redv[w]; ii = redi[w]; }
                labels_f[row] = (float)ii;
            }
            __syncthreads();
        }
    }
}

// ---------------------------------------------------------------------------
// proto_update: literal sequential EMA per class, then L2 renorm.
// ---------------------------------------------------------------------------
__global__ __launch_bounds__(512) void proto_update(
    const float* __restrict__ labels_f, const float* __restrict__ feats_q,
    const float* __restrict__ proto, float* __restrict__ new_proto)
{
    __shared__ int lab[B_SZ];
    __shared__ float red[8];
    __shared__ float rinv_s;
    const int c = blockIdx.x;
    const int t = threadIdx.x;
    for (int i = t; i < B_SZ; i += 512) lab[i] = (int)labels_f[i];
    __syncthreads();
    float val = proto[(size_t)c * F_SZ + t];
    for (int i = 0; i < B_SZ; ++i) {
        if (lab[i] == c)
            val = PROTO_W * val + (1.0f - PROTO_W) * feats_q[(size_t)i * F_SZ + t];
    }
    float sq = val * val;
#pragma unroll
    for (int off = 32; off; off >>= 1) sq += __shfl_down(sq, off);
    if ((t & 63) == 0) red[t >> 6] = sq;
    __syncthreads();
    if (t == 0) {
        float s = 0.0f;
#pragma unroll
        for (int w = 0; w < 8; ++w) s += red[w];
        rinv_s = 1.0f / sqrtf(s);
    }
    __syncthreads();
    new_proto[(size_t)c * F_SZ + t] = val * rinv_s;
}

// ---------------------------------------------------------------------------
// fc_proto: scores = new_proto @ W_fc + b_fc
// ---------------------------------------------------------------------------
__global__ __launch_bounds__(256) void fc_proto(
    const float* __restrict__ new_proto, const float* __restrict__ W_fc,
    const float* __restrict__ b_fc, float* __restrict__ scores)
{
    __shared__ __align__(16) float ps[8][F_SZ];
    const int t = threadIdx.x;
    const int r0 = blockIdx.x * 8;
#pragma unroll
    for (int j = 0; j < 4; ++j) {
        int f4 = t + j * 256;
        int row = f4 >> 7;
        int col = (f4 & 127) * 4;
        int rr = r0 + row;
        if (rr >= C_SZ) rr = C_SZ - 1;
        *(float4*)&ps[row][col] = *(const float4*)&new_proto[(size_t)rr * F_SZ + col];
    }
    __syncthreads();
    const int c0 = t;
    const int c1 = t + 256;
    float acc0[8] = {};
    float acc1[8] = {};
#pragma unroll 4
    for (int k = 0; k < F_SZ; ++k) {
        float w0 = W_fc[k * C_SZ + c0];
        float w1 = (c1 < C_SZ) ? W_fc[k * C_SZ + c1] : 0.0f;
#pragma unroll
        for (int r = 0; r < 8; ++r) {
            float f = ps[r][k];
            acc0[r] += f * w0;
            acc1[r] += f * w1;
        }
    }
    float bb0 = b_fc[c0];
    float bb1 = (c1 < C_SZ) ? b_fc[c1] : 0.0f;
#pragma unroll
    for (int r = 0; r < 8; ++r) {
        if (r0 + r < C_SZ) {
            scores[(size_t)(r0 + r) * C_SZ + c0] = acc0[r] + bb0;
            if (c1 < C_SZ) scores[(size_t)(r0 + r) * C_SZ + c1] = acc1[r] + bb1;
        }
    }
}

// ---------------------------------------------------------------------------
extern "C" void kernel_launch(void* const* d_in, const int* in_sizes, int n_in,
                              void* d_out, int out_size, void* d_ws, size_t ws_size,
                              hipStream_t stream)
{
    const float* img_q     = (const float*)d_in[0];
    const float* img_q1    = (const float*)d_in[1];
    const float* partial_Y = (const float*)d_in[2];
    const float* W_enc     = (const float*)d_in[3];
    const float* W_fc      = (const float*)d_in[4];
    const float* b_fc      = (const float*)d_in[5];
    const float* proto     = (const float*)d_in[6];

    float* out       = (float*)d_out;
    float* logits    = out;            // [2048][345]
    float* new_proto = out + 706560;   // [345][512]
    float* scores    = out + 883200;   // [345][345]
    float* labels_f  = out + 1002225;  // [1024]
    float* feats     = out + 1003249;  // [2048][512]

    char* ws = (char*)d_ws;
    if (ws_size >= (size_t)WS_NEED) {
        short* Xh = (short*)(ws + WS_XH);
        short* Xl = (short*)(ws + WS_XL);
        short* Wh = (short*)(ws + WS_WH);
        short* Wl = (short*)(ws + WS_WL);
        float* P  = (float*)(ws + WS_P);
        hipLaunchKernelGGL(convert_x, dim3(2048), dim3(256), 0, stream,
                           img_q, img_q1, Xh, Xl);
        hipLaunchKernelGGL(convert_w, dim3(128, 8), dim3(256), 0, stream,
                           W_enc, Wh, Wl);
        hipLaunchKernelGGL(gemm_ws, dim3(8, 32, 2), dim3(256), 0, stream,
                           Xh, Xl, Wh, Wl, P);
        hipLaunchKernelGGL(reduce_feats, dim3(1024), dim3(256), 0, stream,
                           P, feats);
    } else {
        hipLaunchKernelGGL(gemm_enc_mfma, dim3(8, 32), dim3(256), 0, stream,
                           img_q, img_q1, W_enc, feats);
    }
    hipLaunchKernelGGL(fc_logits_fused, dim3(512), dim3(256), 0, stream,
                       feats, W_fc, b_fc, partial_Y, logits, labels_f);
    hipLaunchKernelGGL(proto_update, dim3(345), dim3(512), 0, stream,
                       labels_f, feats /* rows 0..1023 = feats_q */, proto, new_proto);
    hipLaunchKernelGGL(fc_proto, dim3(44), dim3(256), 0, stream,
                       new_proto, W_fc, b_fc, scores);
}

// Round 4
// 309.381 us; speedup vs baseline: 2.3515x; 1.2509x over previous
//
#include <hip/hip_runtime.h>
#include <float.h>
#include <math.h>

// Problem constants
#define B_SZ 1024
#define D_SZ 8192
#define C_SZ 345
#define F_SZ 512
#define PROTO_W 0.99f

// d_out layout (float32, flat, reference return order):
//   logits   [2048][345]  @ 0
//   new_proto[345][512]   @ 706560
//   scores   [345][345]   @ 883200
//   labels   [1024]       @ 1002225  (stored as float)
//   feats    [2048][512]  @ 1003249

// d_ws layout (bytes):
//   Xh  [2048][8192] bf16 @ 0          (33,554,432)
//   Xl  [2048][8192] bf16 @ 33554432
//   Wh  [512][8192]  bf16 @ 67108864   (tile-transposed: [n][k])
//   Wl  [512][8192]  bf16 @ 75497472
//   P   [2][2048][512] f32 @ 83886080  (split-K partials)
// Overlay region (reuses Xh space AFTER gemm_ws consumed it; stream-ordered):
//   Fh  [2048][512] bf16 @ 0
//   Fl  [2048][512] bf16 @ 2097152
//   Wth [384][512]  bf16 @ 4194304   (W_fc^T, rows>=345 zero)
//   Wtl [384][512]  bf16 @ 4587520
//   NPh [384][512]  bf16 @ 4980736   (new_proto, rows>=345 never read)
//   NPl [384][512]  bf16 @ 5373952
#define WS_XH 0
#define WS_XL 33554432u
#define WS_WH 67108864u
#define WS_WL 75497472u
#define WS_P  83886080u
#define WS_NEED 92274688u
#define WS_FH  0u
#define WS_FL  2097152u
#define WS_WFH 4194304u
#define WS_WFL 4587520u
#define WS_NPH 4980736u
#define WS_NPL 5373952u

typedef short bf16x8 __attribute__((ext_vector_type(8)));
typedef short short4v __attribute__((ext_vector_type(4)));
typedef short short8v __attribute__((ext_vector_type(8)));
typedef float f32x4  __attribute__((ext_vector_type(4)));

__device__ __forceinline__ void split_bf16(float x, short& hi, short& lo) {
    unsigned u = __float_as_uint(x);
    unsigned r = (u + 0x7FFFu + ((u >> 16) & 1u)) >> 16;
    hi = (short)r;
    float hf = __uint_as_float(r << 16);
    lo = (short)(__float_as_uint(x - hf) >> 16);
}

__device__ __forceinline__ void gl_lds16(const short* g, short* l) {
    __builtin_amdgcn_global_load_lds(
        (const __attribute__((address_space(1))) void*)g,
        (__attribute__((address_space(3))) void*)l, 16, 0, 0);
}

#define MFMA_BF16 __builtin_amdgcn_mfma_f32_16x16x32_bf16

// 12-MFMA bf16x3 block over one 32-k sub-tile; expects sAh/sAl/sBh/sBl LDS
// arrays and f32x4 acc[2][2] in scope.
#define MFMA_BLOCK(IA0, IA1, IB0, IB1)                                   \
    do {                                                                 \
        bf16x8 a0h = *(const bf16x8*)&sAh[IA0];                          \
        bf16x8 a1h = *(const bf16x8*)&sAh[IA1];                          \
        bf16x8 b0h = *(const bf16x8*)&sBh[IB0];                          \
        bf16x8 b1h = *(const bf16x8*)&sBh[IB1];                          \
        bf16x8 a0l = *(const bf16x8*)&sAl[IA0];                          \
        bf16x8 a1l = *(const bf16x8*)&sAl[IA1];                          \
        bf16x8 b0l = *(const bf16x8*)&sBl[IB0];                          \
        bf16x8 b1l = *(const bf16x8*)&sBl[IB1];                          \
        acc[0][0] = MFMA_BF16(a0h, b0h, acc[0][0], 0, 0, 0);             \
        acc[0][1] = MFMA_BF16(a0h, b1h, acc[0][1], 0, 0, 0);             \
        acc[1][0] = MFMA_BF16(a1h, b0h, acc[1][0], 0, 0, 0);             \
        acc[1][1] = MFMA_BF16(a1h, b1h, acc[1][1], 0, 0, 0);             \
        acc[0][0] = MFMA_BF16(a0h, b0l, acc[0][0], 0, 0, 0);             \
        acc[0][1] = MFMA_BF16(a0h, b1l, acc[0][1], 0, 0, 0);             \
        acc[1][0] = MFMA_BF16(a1h, b0l, acc[1][0], 0, 0, 0);             \
        acc[1][1] = MFMA_BF16(a1h, b1l, acc[1][1], 0, 0, 0);             \
        acc[0][0] = MFMA_BF16(a0l, b0h, acc[0][0], 0, 0, 0);             \
        acc[0][1] = MFMA_BF16(a0l, b1h, acc[0][1], 0, 0, 0);             \
        acc[1][0] = MFMA_BF16(a1l, b0h, acc[1][0], 0, 0, 0);             \
        acc[1][1] = MFMA_BF16(a1l, b1h, acc[1][1], 0, 0, 0);             \
    } while (0)

// ---------------------------------------------------------------------------
// convert_x: X fp32 -> Xh/Xl bf16
// ---------------------------------------------------------------------------
__global__ __launch_bounds__(256) void convert_x(
    const float* __restrict__ img_q, const float* __restrict__ img_q1,
    short* __restrict__ Xh, short* __restrict__ Xl)
{
    const int HALF = (B_SZ * D_SZ) / 4;
    const int total = 2 * HALF;
    for (int i4 = blockIdx.x * 256 + threadIdx.x; i4 < total; i4 += gridDim.x * 256) {
        float4 v = (i4 < HALF) ? ((const float4*)img_q)[i4]
                               : ((const float4*)img_q1)[i4 - HALF];
        short4v h, l;
        short hh, ll;
        split_bf16(v.x, hh, ll); h.x = hh; l.x = ll;
        split_bf16(v.y, hh, ll); h.y = hh; l.y = ll;
        split_bf16(v.z, hh, ll); h.z = hh; l.z = ll;
        split_bf16(v.w, hh, ll); h.w = hh; l.w = ll;
        ((short4v*)Xh)[i4] = h;
        ((short4v*)Xl)[i4] = l;
    }
}

// ---------------------------------------------------------------------------
// convert_w: W_enc[k][n] fp32 -> Wh/Wl[n][k] bf16 (transposed via LDS tile)
// ---------------------------------------------------------------------------
__global__ __launch_bounds__(256) void convert_w(
    const float* __restrict__ W_enc, short* __restrict__ Wh, short* __restrict__ Wl)
{
    __shared__ float tile[64][65];
    const int k0 = blockIdx.x * 64;
    const int n0 = blockIdx.y * 64;
    const int t = threadIdx.x;
    {
        const int kr = t >> 2;
        const int cb = (t & 3) * 16;
#pragma unroll
        for (int j = 0; j < 4; ++j) {
            float4 v = *(const float4*)&W_enc[(size_t)(k0 + kr) * F_SZ + n0 + cb + j * 4];
            tile[kr][cb + j * 4 + 0] = v.x;
            tile[kr][cb + j * 4 + 1] = v.y;
            tile[kr][cb + j * 4 + 2] = v.z;
            tile[kr][cb + j * 4 + 3] = v.w;
        }
    }
    __syncthreads();
    const int n = t >> 2;
#pragma unroll
    for (int cc = 0; cc < 2; ++cc) {
        const int ch = (t & 3) * 2 + cc;
        short8v h, l;
#pragma unroll
        for (int e = 0; e < 8; ++e) {
            short hh, ll;
            split_bf16(tile[ch * 8 + e][n], hh, ll);
            h[e] = hh; l[e] = ll;
        }
        size_t off = (size_t)(n0 + n) * D_SZ + k0 + ch * 8;
        *(short8v*)&Wh[off] = h;
        *(short8v*)&Wl[off] = l;
    }
}

// ---------------------------------------------------------------------------
// gemm_ws: P[ks] = A(64 x 4096) @ B(4096 x 64), bf16x3, split-K=2.
// grid (8, 32, 2), 256 threads (4 waves, 32x32 quadrant each).
// ---------------------------------------------------------------------------
__global__ __launch_bounds__(256) void gemm_ws(
    const short* __restrict__ Xh, const short* __restrict__ Xl,
    const short* __restrict__ Wh, const short* __restrict__ Wl,
    float* __restrict__ P)
{
    __shared__ __align__(16) short sAh[4096];
    __shared__ __align__(16) short sAl[4096];
    __shared__ __align__(16) short sBh[4096];
    __shared__ __align__(16) short sBl[4096];

    const int t = threadIdx.x;
    const int lane = t & 63;
    const int wave = t >> 6;
    const int nt = blockIdx.x;
    const int mt = blockIdx.y;
    const int ks = blockIdx.z;
    const int m0 = mt * 64;
    const int kbase = ks * 4096;

    const short* gbase =
        (wave == 0) ? Xh + (size_t)m0 * D_SZ :
        (wave == 1) ? Xl + (size_t)m0 * D_SZ :
        (wave == 2) ? Wh + (size_t)nt * 64 * D_SZ :
                      Wl + (size_t)nt * 64 * D_SZ;
    short* lbase = (wave == 0) ? sAh : (wave == 1) ? sAl : (wave == 2) ? sBh : sBl;
    const int lrow8 = lane >> 3;
    const int colOff = ((lane & 7) ^ lrow8) * 8;
    const short* gsrc = gbase + (size_t)lrow8 * D_SZ + kbase + colOff;

    const int mo = (wave >> 1) * 32;
    const int no = (wave & 1) * 32;
    const int lr = lane & 15;
    const int lkg = lane >> 4;
    const int x7 = lr & 7;
    const int sl0 = (0 + lkg) ^ x7;
    const int sl1 = (4 + lkg) ^ x7;
    const int ra0 = (mo + lr) * 64,      ra1 = (mo + 16 + lr) * 64;
    const int rb0 = (no + lr) * 64,      rb1 = (no + 16 + lr) * 64;
    const int a00 = ra0 + sl0 * 8, a01 = ra0 + sl1 * 8;
    const int a10 = ra1 + sl0 * 8, a11 = ra1 + sl1 * 8;
    const int b00 = rb0 + sl0 * 8, b01 = rb0 + sl1 * 8;
    const int b10 = rb1 + sl0 * 8, b11 = rb1 + sl1 * 8;

    f32x4 acc[2][2] = {};

    for (int s = 0; s < 64; ++s) {
        __syncthreads();
#pragma unroll
        for (int j = 0; j < 8; ++j)
            gl_lds16(gsrc + (size_t)(8 * j) * D_SZ + s * 64, lbase + j * 512);
        __syncthreads();
        MFMA_BLOCK(a00, a10, b00, b10);
        MFMA_BLOCK(a01, a11, b01, b11);
    }

    float* Pout = P + (size_t)ks * (2048u * 512u);
#pragma unroll
    for (int f = 0; f < 2; ++f)
#pragma unroll
        for (int g = 0; g < 2; ++g) {
            const int col  = nt * 64 + no + g * 16 + (lane & 15);
            const int row0 = m0 + mo + f * 16 + (lane >> 4) * 4;
#pragma unroll
            for (int r = 0; r < 4; ++r)
                Pout[(size_t)(row0 + r) * F_SZ + col] = acc[f][g][r];
        }
}

// ---------------------------------------------------------------------------
// reduce_feats_split: feats = P0 + P1 (fp32, scalar stores: feats base is
// only 4B-aligned) and Fh/Fl bf16 hi/lo for the fc MFMA.
// ---------------------------------------------------------------------------
__global__ __launch_bounds__(256) void reduce_feats_split(
    const float* __restrict__ P, float* __restrict__ feats,
    short* __restrict__ Fh, short* __restrict__ Fl)
{
    const int n4 = (2048 * 512) / 4;
    const float* P1 = P + 2048 * 512;
    for (int i4 = blockIdx.x * 256 + threadIdx.x; i4 < n4; i4 += gridDim.x * 256) {
        float4 a = ((const float4*)P)[i4];
        float4 b = ((const float4*)P1)[i4];
        float v[4] = {a.x + b.x, a.y + b.y, a.z + b.z, a.w + b.w};
        short4v h, l;
        short hh, ll;
#pragma unroll
        for (int e = 0; e < 4; ++e) {
            feats[i4 * 4 + e] = v[e];
            split_bf16(v[e], hh, ll); h[e] = hh; l[e] = ll;
        }
        ((short4v*)Fh)[i4] = h;
        ((short4v*)Fl)[i4] = l;
    }
}

// ---------------------------------------------------------------------------
// convert_wfc: W_fc[512][345] fp32 -> Wth/Wtl[384][512] bf16 (transposed,
// rows >= 345 zero-filled). grid (8 k-tiles, 6 c-tiles), 256 threads.
// ---------------------------------------------------------------------------
__global__ __launch_bounds__(256) void convert_wfc(
    const float* __restrict__ W_fc, short* __restrict__ Wth, short* __restrict__ Wtl)
{
    __shared__ float tile[64][65];
    const int k0 = blockIdx.x * 64;
    const int c0 = blockIdx.y * 64;
    const int t = threadIdx.x;
    for (int idx = t; idx < 64 * 64; idx += 256) {
        const int kr = idx >> 6;
        const int cc = idx & 63;
        tile[kr][cc] = (c0 + cc < C_SZ) ? W_fc[(size_t)(k0 + kr) * C_SZ + c0 + cc] : 0.0f;
    }
    __syncthreads();
    const int crow = t >> 2;
#pragma unroll
    for (int cc2 = 0; cc2 < 2; ++cc2) {
        const int ch = (t & 3) * 2 + cc2;
        short8v h, l;
#pragma unroll
        for (int e = 0; e < 8; ++e) {
            short hh, ll;
            split_bf16(tile[ch * 8 + e][crow], hh, ll);
            h[e] = hh; l[e] = ll;
        }
        size_t off = (size_t)(c0 + crow) * F_SZ + k0 + ch * 8;
        *(short8v*)&Wth[off] = h;
        *(short8v*)&Wtl[off] = l;
    }
}

// ---------------------------------------------------------------------------
// gemm_fc: Cout[M][345] = A[M][512] @ B^T (B = [384][512] row-per-col) + bias
// bf16x3 MFMA, 64x64 tile, BK=64 x 8 steps. A rows clamped to M-1 for loads;
// stores masked (row<M, col<345). grid (6, ceil(M/64)).
// ---------------------------------------------------------------------------
__global__ __launch_bounds__(256) void gemm_fc(
    const short* __restrict__ Ah, const short* __restrict__ Al,
    const short* __restrict__ Bh, const short* __restrict__ Bl,
    const float* __restrict__ bias, float* __restrict__ Cout, int M)
{
    __shared__ __align__(16) short sAh[4096];
    __shared__ __align__(16) short sAl[4096];
    __shared__ __align__(16) short sBh[4096];
    __shared__ __align__(16) short sBl[4096];

    const int t = threadIdx.x;
    const int lane = t & 63;
    const int wave = t >> 6;
    const int n0 = blockIdx.x * 64;
    const int m0 = blockIdx.y * 64;

    const int lrow8 = lane >> 3;
    const int colOff = ((lane & 7) ^ lrow8) * 8;

    short* lbase = (wave == 0) ? sAh : (wave == 1) ? sAl : (wave == 2) ? sBh : sBl;
    const short* gA = (wave == 1) ? Al : Ah;
    const short* gB = (wave == 3) ? Bl : Bh;
    const bool isA = wave < 2;

    const int mo = (wave >> 1) * 32;
    const int no = (wave & 1) * 32;
    const int lr = lane & 15;
    const int lkg = lane >> 4;
    const int x7 = lr & 7;
    const int sl0 = (0 + lkg) ^ x7;
    const int sl1 = (4 + lkg) ^ x7;
    const int ra0 = (mo + lr) * 64,      ra1 = (mo + 16 + lr) * 64;
    const int rb0 = (no + lr) * 64,      rb1 = (no + 16 + lr) * 64;
    const int a00 = ra0 + sl0 * 8, a01 = ra0 + sl1 * 8;
    const int a10 = ra1 + sl0 * 8, a11 = ra1 + sl1 * 8;
    const int b00 = rb0 + sl0 * 8, b01 = rb0 + sl1 * 8;
    const int b10 = rb1 + sl0 * 8, b11 = rb1 + sl1 * 8;

    f32x4 acc[2][2] = {};

    for (int s = 0; s < 8; ++s) {
        __syncthreads();
        if (isA) {
#pragma unroll
            for (int j = 0; j < 8; ++j) {
                int row = m0 + lrow8 + 8 * j;
                if (row > M - 1) row = M - 1;
                gl_lds16(gA + (size_t)row * F_SZ + s * 64 + colOff, lbase + j * 512);
            }
        } else {
#pragma unroll
            for (int j = 0; j < 8; ++j) {
                int row = n0 + lrow8 + 8 * j;   // < 384, allocated
                gl_lds16(gB + (size_t)row * F_SZ + s * 64 + colOff, lbase + j * 512);
            }
        }
        __syncthreads();
        MFMA_BLOCK(a00, a10, b00, b10);
        MFMA_BLOCK(a01, a11, b01, b11);
    }

#pragma unroll
    for (int f = 0; f < 2; ++f)
#pragma unroll
        for (int g = 0; g < 2; ++g) {
            const int col  = n0 + no + g * 16 + (lane & 15);
            if (col >= C_SZ) continue;
            const float bb = bias[col];
            const int row0 = m0 + mo + f * 16 + (lane >> 4) * 4;
#pragma unroll
            for (int r = 0; r < 4; ++r) {
                const int row = row0 + r;
                if (row < M)
                    Cout[(size_t)row * C_SZ + col] = acc[f][g][r] + bb;
            }
        }
}

// ---------------------------------------------------------------------------
// argmax_labels: masked argmax per row (softmax+renorm preserve argmax).
// ---------------------------------------------------------------------------
__global__ __launch_bounds__(64) void argmax_labels(
    const float* __restrict__ logits, const float* __restrict__ partial_Y,
    float* __restrict__ labels_f)
{
    const int i = blockIdx.x;
    const int lane = threadIdx.x;
    float best = -FLT_MAX;
    int bidx = C_SZ;
    for (int c = lane; c < C_SZ; c += 64) {
        if (partial_Y[(size_t)i * C_SZ + c] != 0.0f) {
            float v = logits[(size_t)i * C_SZ + c];
            if (v > best || (v == best && c < bidx)) { best = v; bidx = c; }
        }
    }
#pragma unroll
    for (int off = 32; off; off >>= 1) {
        float ov = __shfl_down(best, off);
        int oi = __shfl_down(bidx, off);
        if (ov > best || (ov == best && oi < bidx)) { best = ov; bidx = oi; }
    }
    if (lane == 0) labels_f[i] = (float)bidx;
}

// ---------------------------------------------------------------------------
// proto_update: literal sequential EMA per class, L2 renorm; also emits
// bf16 hi/lo of new_proto for the scores MFMA (if NPh != nullptr).
// ---------------------------------------------------------------------------
__global__ __launch_bounds__(512) void proto_update(
    const float* __restrict__ labels_f, const float* __restrict__ feats_q,
    const float* __restrict__ proto, float* __restrict__ new_proto,
    short* __restrict__ NPh, short* __restrict__ NPl)
{
    __shared__ int lab[B_SZ];
    __shared__ float red[8];
    __shared__ float rinv_s;
    const int c = blockIdx.x;
    const int t = threadIdx.x;
    for (int i = t; i < B_SZ; i += 512) lab[i] = (int)labels_f[i];
    __syncthreads();
    float val = proto[(size_t)c * F_SZ + t];
    for (int i = 0; i < B_SZ; ++i) {
        if (lab[i] == c)
            val = PROTO_W * val + (1.0f - PROTO_W) * feats_q[(size_t)i * F_SZ + t];
    }
    float sq = val * val;
#pragma unroll
    for (int off = 32; off; off >>= 1) sq += __shfl_down(sq, off);
    if ((t & 63) == 0) red[t >> 6] = sq;
    __syncthreads();
    if (t == 0) {
        float s = 0.0f;
#pragma unroll
        for (int w = 0; w < 8; ++w) s += red[w];
        rinv_s = 1.0f / sqrtf(s);
    }
    __syncthreads();
    const float v = val * rinv_s;
    new_proto[(size_t)c * F_SZ + t] = v;
    if (NPh) {
        short hh, ll;
        split_bf16(v, hh, ll);
        NPh[(size_t)c * F_SZ + t] = hh;
        NPl[(size_t)c * F_SZ + t] = ll;
    }
}

// ---------------------------------------------------------------------------
// Fallback path kernels (only if ws_size is insufficient) — proven R2/R3 code.
// ---------------------------------------------------------------------------
#define LDA 40
__global__ __launch_bounds__(256) void gemm_enc_mfma(
    const float* __restrict__ img_q, const float* __restrict__ img_q1,
    const float* __restrict__ W_enc, float* __restrict__ feats)
{
    __shared__ __align__(16) short Ah[2][64 * LDA];
    __shared__ __align__(16) short Al[2][64 * LDA];
    __shared__ __align__(16) short Bh[2][64 * LDA];
    __shared__ __align__(16) short Bl[2][64 * LDA];
    const int t = threadIdx.x;
    const int nBase = blockIdx.x * 64;
    const int mBase = blockIdx.y * 64;
    const float* X = (mBase < B_SZ) ? (img_q + (size_t)mBase * D_SZ)
                                    : (img_q1 + (size_t)(mBase - B_SZ) * D_SZ);
    const int arow = t >> 2;
    const int akq  = t & 3;
    const int bn   = t & 63;
    const int bkg  = t >> 6;
    const int bsw  = (bkg + (bn >> 3)) & 3;
    const float* aptr = X + (size_t)arow * D_SZ + akq * 8;
    const float* bptr = W_enc + (size_t)(bkg * 8) * F_SZ + nBase + bn;
    const int wave = t >> 6;
    const int lane = t & 63;
    const int mo   = (wave >> 1) * 32;
    const int no   = (wave & 1) * 32;
    const int lrow = lane & 15;
    const int lkg  = lane >> 4;
    f32x4 acc[2][2] = {};
    {
        float4 av0 = *(const float4*)(aptr);
        float4 av1 = *(const float4*)(aptr + 4);
        float bv[8];
#pragma unroll
        for (int i = 0; i < 8; ++i) bv[i] = bptr[(size_t)i * F_SZ];
        bf16x8 h, l;
        float va[8] = {av0.x, av0.y, av0.z, av0.w, av1.x, av1.y, av1.z, av1.w};
#pragma unroll
        for (int i = 0; i < 8; ++i) { short hh, ll; split_bf16(va[i], hh, ll); h[i] = hh; l[i] = ll; }
        *(bf16x8*)&Ah[0][arow * LDA + akq * 8] = h;
        *(bf16x8*)&Al[0][arow * LDA + akq * 8] = l;
#pragma unroll
        for (int i = 0; i < 8; ++i) { short hh, ll; split_bf16(bv[i], hh, ll); h[i] = hh; l[i] = ll; }
        *(bf16x8*)&Bh[0][bn * LDA + bsw * 8] = h;
        *(bf16x8*)&Bl[0][bn * LDA + bsw * 8] = l;
    }
    __syncthreads();
    const int aoff0 = (mo + lrow) * LDA + lkg * 8;
    const int aoff1 = (mo + 16 + lrow) * LDA + lkg * 8;
    const int bnn0  = no + lrow;
    const int bnn1  = no + 16 + lrow;
    const int boff0 = bnn0 * LDA + ((lkg + (bnn0 >> 3)) & 3) * 8;
    const int boff1 = bnn1 * LDA + ((lkg + (bnn1 >> 3)) & 3) * 8;
    int buf = 0;
    for (int s = 0; s < 256; ++s) {
        float4 na0, na1; float nb[8];
        const bool more = (s + 1 < 256);
        if (more) {
            const float* ap = aptr + (size_t)(s + 1) * 32;
            na0 = *(const float4*)(ap);
            na1 = *(const float4*)(ap + 4);
            const float* bp = bptr + (size_t)(s + 1) * 32 * F_SZ;
#pragma unroll
            for (int i = 0; i < 8; ++i) nb[i] = bp[(size_t)i * F_SZ];
        }
        bf16x8 a0h = *(bf16x8*)&Ah[buf][aoff0];
        bf16x8 a1h = *(bf16x8*)&Ah[buf][aoff1];
        bf16x8 a0l = *(bf16x8*)&Al[buf][aoff0];
        bf16x8 a1l = *(bf16x8*)&Al[buf][aoff1];
        bf16x8 b0h = *(bf16x8*)&Bh[buf][boff0];
        bf16x8 b1h = *(bf16x8*)&Bh[buf][boff1];
        bf16x8 b0l = *(bf16x8*)&Bl[buf][boff0];
        bf16x8 b1l = *(bf16x8*)&Bl[buf][boff1];
        acc[0][0] = MFMA_BF16(a0h, b0h, acc[0][0], 0, 0, 0);
        acc[0][1] = MFMA_BF16(a0h, b1h, acc[0][1], 0, 0, 0);
        acc[1][0] = MFMA_BF16(a1h, b0h, acc[1][0], 0, 0, 0);
        acc[1][1] = MFMA_BF16(a1h, b1h, acc[1][1], 0, 0, 0);
        acc[0][0] = MFMA_BF16(a0h, b0l, acc[0][0], 0, 0, 0);
        acc[0][1] = MFMA_BF16(a0h, b1l, acc[0][1], 0, 0, 0);
        acc[1][0] = MFMA_BF16(a1h, b0l, acc[1][0], 0, 0, 0);
        acc[1][1] = MFMA_BF16(a1h, b1l, acc[1][1], 0, 0, 0);
        acc[0][0] = MFMA_BF16(a0l, b0h, acc[0][0], 0, 0, 0);
        acc[0][1] = MFMA_BF16(a0l, b1h, acc[0][1], 0, 0, 0);
        acc[1][0] = MFMA_BF16(a1l, b0h, acc[1][0], 0, 0, 0);
        acc[1][1] = MFMA_BF16(a1l, b1h, acc[1][1], 0, 0, 0);
        if (more) {
            bf16x8 h, l;
            float va[8] = {na0.x, na0.y, na0.z, na0.w, na1.x, na1.y, na1.z, na1.w};
#pragma unroll
            for (int i = 0; i < 8; ++i) { short hh, ll; split_bf16(va[i], hh, ll); h[i] = hh; l[i] = ll; }
            *(bf16x8*)&Ah[buf ^ 1][arow * LDA + akq * 8] = h;
            *(bf16x8*)&Al[buf ^ 1][arow * LDA + akq * 8] = l;
#pragma unroll
            for (int i = 0; i < 8; ++i) { short hh, ll; split_bf16(nb[i], hh, ll); h[i] = hh; l[i] = ll; }
            *(bf16x8*)&Bh[buf ^ 1][bn * LDA + bsw * 8] = h;
            *(bf16x8*)&Bl[buf ^ 1][bn * LDA + bsw * 8] = l;
        }
        __syncthreads();
        buf ^= 1;
    }
#pragma unroll
    for (int f = 0; f < 2; ++f)
#pragma unroll
        for (int g = 0; g < 2; ++g) {
            const int col  = nBase + no + g * 16 + (lane & 15);
            const int row0 = mBase + mo + f * 16 + (lane >> 4) * 4;
#pragma unroll
            for (int r = 0; r < 4; ++r)
                feats[(size_t)(row0 + r) * F_SZ + col] = acc[f][g][r];
        }
}

__global__ __launch_bounds__(256) void fc_logits_fused(
    const float* __restrict__ feats, const float* __restrict__ W_fc,
    const float* __restrict__ b_fc, const float* __restrict__ partial_Y,
    float* __restrict__ logits, float* __restrict__ labels_f)
{
    __shared__ __align__(16) float fs[4][F_SZ];
    __shared__ float redv[4];
    __shared__ int   redi[4];
    const int t = threadIdx.x;
    const int r0 = blockIdx.x * 4;
#pragma unroll
    for (int j = 0; j < 2; ++j) {
        int f4 = t + j * 256;
        int row = f4 >> 7;
        int col = (f4 & 127) * 4;
        *(float4*)&fs[row][col] = *(const float4*)&feats[(size_t)(r0 + row) * F_SZ + col];
    }
    __syncthreads();
    const int c0 = t;
    const int c1 = t + 256;
    float acc0[4] = {};
    float acc1[4] = {};
#pragma unroll 4
    for (int k = 0; k < F_SZ; ++k) {
        float w0 = W_fc[k * C_SZ + c0];
        float w1 = (c1 < C_SZ) ? W_fc[k * C_SZ + c1] : 0.0f;
#pragma unroll
        for (int r = 0; r < 4; ++r) {
            float f = fs[r][k];
            acc0[r] += f * w0;
            acc1[r] += f * w1;
        }
    }
    float v0[4], v1[4];
    const float bb0 = b_fc[c0];
    const float bb1 = (c1 < C_SZ) ? b_fc[c1] : 0.0f;
#pragma unroll
    for (int r = 0; r < 4; ++r) {
        v0[r] = acc0[r] + bb0;
        logits[(size_t)(r0 + r) * C_SZ + c0] = v0[r];
        if (c1 < C_SZ) {
            v1[r] = acc1[r] + bb1;
            logits[(size_t)(r0 + r) * C_SZ + c1] = v1[r];
        }
    }
    if (r0 < B_SZ) {
#pragma unroll
        for (int r = 0; r < 4; ++r) {
            const int row = r0 + r;
            float best = -FLT_MAX; int bi = C_SZ;
            if (partial_Y[(size_t)row * C_SZ + c0] != 0.0f) { best = v0[r]; bi = c0; }
            if (c1 < C_SZ && partial_Y[(size_t)row * C_SZ + c1] != 0.0f && v1[r] > best) {
                best = v1[r]; bi = c1;
            }
#pragma unroll
            for (int off = 32; off; off >>= 1) {
                float ov = __shfl_down(best, off);
                int oi = __shfl_down(bi, off);
                if (ov > best || (ov == best && oi < bi)) { best = ov; bi = oi; }
            }
            if ((t & 63) == 0) { redv[t >> 6] = best; redi[t >> 6] = bi; }
            __syncthreads();
            if (t == 0) {
                float bb = redv[0]; int ii = redi[0];
#pragma unroll
                for (int w = 1; w < 4; ++w)
                    if (redv[w] > bb || (redv[w] == bb && redi[w] < ii)) { bb = redv[w]; ii = redi[w]; }
                labels_f[row] = (float)ii;
            }
            __syncthreads();
        }
    }
}

__global__ __launch_bounds__(256) void fc_proto(
    const float* __restrict__ new_proto, const float* __restrict__ W_fc,
    const float* __restrict__ b_fc, float* __restrict__ scores)
{
    __shared__ __align__(16) float ps[8][F_SZ];
    const int t = threadIdx.x;
    const int r0 = blockIdx.x * 8;
#pragma unroll
    for (int j = 0; j < 4; ++j) {
        int f4 = t + j * 256;
        int row = f4 >> 7;
        int col = (f4 & 127) * 4;
        int rr = r0 + row;
        if (rr >= C_SZ) rr = C_SZ - 1;
        *(float4*)&ps[row][col] = *(const float4*)&new_proto[(size_t)rr * F_SZ + col];
    }
    __syncthreads();
    const int c0 = t;
    const int c1 = t + 256;
    float acc0[8] = {};
    float acc1[8] = {};
#pragma unroll 4
    for (int k = 0; k < F_SZ; ++k) {
        float w0 = W_fc[k * C_SZ + c0];
        float w1 = (c1 < C_SZ) ? W_fc[k * C_SZ + c1] : 0.0f;
#pragma unroll
        for (int r = 0; r < 8; ++r) {
            float f = ps[r][k];
            acc0[r] += f * w0;
            acc1[r] += f * w1;
        }
    }
    float bb0 = b_fc[c0];
    float bb1 = (c1 < C_SZ) ? b_fc[c1] : 0.0f;
#pragma unroll
    for (int r = 0; r < 8; ++r) {
        if (r0 + r < C_SZ) {
            scores[(size_t)(r0 + r) * C_SZ + c0] = acc0[r] + bb0;
            if (c1 < C_SZ) scores[(size_t)(r0 + r) * C_SZ + c1] = acc1[r] + bb1;
        }
    }
}

// ---------------------------------------------------------------------------
extern "C" void kernel_launch(void* const* d_in, const int* in_sizes, int n_in,
                              void* d_out, int out_size, void* d_ws, size_t ws_size,
                              hipStream_t stream)
{
    const float* img_q     = (const float*)d_in[0];
    const float* img_q1    = (const float*)d_in[1];
    const float* partial_Y = (const float*)d_in[2];
    const float* W_enc     = (const float*)d_in[3];
    const float* W_fc      = (const float*)d_in[4];
    const float* b_fc      = (const float*)d_in[5];
    const float* proto     = (const float*)d_in[6];

    float* out       = (float*)d_out;
    float* logits    = out;            // [2048][345]
    float* new_proto = out + 706560;   // [345][512]
    float* scores    = out + 883200;   // [345][345]
    float* labels_f  = out + 1002225;  // [1024]
    float* feats     = out + 1003249;  // [2048][512]

    char* ws = (char*)d_ws;
    if (ws_size >= (size_t)WS_NEED) {
        short* Xh  = (short*)(ws + WS_XH);
        short* Xl  = (short*)(ws + WS_XL);
        short* Wh  = (short*)(ws + WS_WH);
        short* Wl  = (short*)(ws + WS_WL);
        float* P   = (float*)(ws + WS_P);
        // overlay region (valid after gemm_ws has consumed Xh/Xl)
        short* Fh  = (short*)(ws + WS_FH);
        short* Fl  = (short*)(ws + WS_FL);
        short* Wth = (short*)(ws + WS_WFH);
        short* Wtl = (short*)(ws + WS_WFL);
        short* NPh = (short*)(ws + WS_NPH);
        short* NPl = (short*)(ws + WS_NPL);

        hipLaunchKernelGGL(convert_x, dim3(2048), dim3(256), 0, stream,
                           img_q, img_q1, Xh, Xl);
        hipLaunchKernelGGL(convert_w, dim3(128, 8), dim3(256), 0, stream,
                           W_enc, Wh, Wl);
        hipLaunchKernelGGL(gemm_ws, dim3(8, 32, 2), dim3(256), 0, stream,
                           Xh, Xl, Wh, Wl, P);
        hipLaunchKernelGGL(reduce_feats_split, dim3(1024), dim3(256), 0, stream,
                           P, feats, Fh, Fl);
        hipLaunchKernelGGL(convert_wfc, dim3(8, 6), dim3(256), 0, stream,
                           W_fc, Wth, Wtl);
        hipLaunchKernelGGL(gemm_fc, dim3(6, 32), dim3(256), 0, stream,
                           Fh, Fl, Wth, Wtl, b_fc, logits, 2048);
        hipLaunchKernelGGL(argmax_labels, dim3(1024), dim3(64), 0, stream,
                           logits, partial_Y, labels_f);
        hipLaunchKernelGGL(proto_update, dim3(345), dim3(512), 0, stream,
                           labels_f, feats, proto, new_proto, NPh, NPl);
        hipLaunchKernelGGL(gemm_fc, dim3(6, 6), dim3(256), 0, stream,
                           NPh, NPl, Wth, Wtl, b_fc, scores, C_SZ);
    } else {
        hipLaunchKernelGGL(gemm_enc_mfma, dim3(8, 32), dim3(256), 0, stream,
                           img_q, img_q1, W_enc, feats);
        hipLaunchKernelGGL(fc_logits_fused, dim3(512), dim3(256), 0, stream,
                           feats, W_fc, b_fc, partial_Y, logits, labels_f);
        hipLaunchKernelGGL(proto_update, dim3(345), dim3(512), 0, stream,
                           labels_f, feats, proto, new_proto, (short*)nullptr, (short*)nullptr);
        hipLaunchKernelGGL(fc_proto, dim3(44), dim3(256), 0, stream,
                           new_proto, W_fc, b_fc, scores);
    }
}